// Round 3
// baseline (616.503 us; speedup 1.0000x reference)
//
#include <hip/hip_runtime.h>

// LightGCN encoder on MI355X — round 3.
// CSR pull (round 2) + : bipartite symmetry (build from 1M undirected pairs),
// weights recomputed from degrees (payload int2 -> int), pre-scaled features
// g = norm*h (weight-free pull inner loop), 4-way edge parallelism per node
// with shfl-xor reduction (shorter dependent-load chains).
#define N_USERS 100000
#define N_NODES 150000
#define DIM 64
#define BATCH 4096
#define CHUNK 1024   // scan chunk per block

// --- CSR build -------------------------------------------------------------

// Degree histogram from the first half (undirected pairs): deg[r]++, deg[c]++.
// By symmetry this equals both the reference's bincount(src) and the in-degree.
__global__ void lgcn_hist(const int* __restrict__ row, const int* __restrict__ col,
                          int* __restrict__ deg, int EH) {
    int e = blockIdx.x * blockDim.x + threadIdx.x;
    if (e >= EH) return;
    atomicAdd(&deg[row[e]], 1);
    atomicAdd(&deg[col[e]], 1);
}

// Per-block exclusive scan of CHUNK degrees; block total -> partials[blk].
__global__ void lgcn_scan1(const int* __restrict__ deg, int* __restrict__ rp,
                           int* __restrict__ partials) {
    __shared__ int bufA[CHUNK], bufB[CHUNK];
    int blk = blockIdx.x;
    int base = blk * CHUNK;
    for (int i = threadIdx.x; i < CHUNK; i += blockDim.x) {
        int g = base + i;
        bufA[i] = (g < N_NODES) ? deg[g] : 0;
    }
    __syncthreads();
    int* cur = bufA; int* nxt = bufB;
    for (int off = 1; off < CHUNK; off <<= 1) {
        for (int i = threadIdx.x; i < CHUNK; i += blockDim.x)
            nxt[i] = (i >= off) ? cur[i] + cur[i - off] : cur[i];
        __syncthreads();
        int* t = cur; cur = nxt; nxt = t;
    }
    for (int i = threadIdx.x; i < CHUNK; i += blockDim.x) {
        int g = base + i;
        if (g < N_NODES) rp[g] = (i == 0) ? 0 : cur[i - 1];
    }
    if (threadIdx.x == 0) partials[blk] = cur[CHUNK - 1];
}

// Single-block exclusive scan of the P block totals (P <= CHUNK).
__global__ void lgcn_scan2(int* __restrict__ partials, int P) {
    __shared__ int bufA[CHUNK], bufB[CHUNK];
    for (int i = threadIdx.x; i < CHUNK; i += blockDim.x)
        bufA[i] = (i < P) ? partials[i] : 0;
    __syncthreads();
    int* cur = bufA; int* nxt = bufB;
    for (int off = 1; off < CHUNK; off <<= 1) {
        for (int i = threadIdx.x; i < CHUNK; i += blockDim.x)
            nxt[i] = (i >= off) ? cur[i] + cur[i - off] : cur[i];
        __syncthreads();
        int* t = cur; cur = nxt; nxt = t;
    }
    for (int i = threadIdx.x; i < P; i += blockDim.x)
        partials[i] = (i == 0) ? 0 : cur[i - 1];
}

// Finalize row pointers, init cursors, and compute norm tables:
// da = max(deg,1); norm = 1/sqrt(da); rnorm = sqrt(da).
__global__ void lgcn_scan3(int* __restrict__ rp, const int* __restrict__ partials,
                           int* __restrict__ cursor, const int* __restrict__ deg,
                           float* __restrict__ norm, float* __restrict__ rnorm, int E) {
    int g = blockIdx.x * blockDim.x + threadIdx.x;
    if (g < N_NODES) {
        int v = rp[g] + partials[g >> 10];
        rp[g] = v;
        cursor[g] = v;
        int d = deg[g];
        float da = (d == 0) ? 1.0f : (float)d;
        float sq = sqrtf(da);
        norm[g] = 1.0f / sq;
        rnorm[g] = sq;
    } else if (g == N_NODES) {
        rp[g] = E;
    }
}

// Fill both directions from the undirected pair list: packed holds src only.
__global__ void lgcn_fill(const int* __restrict__ row, const int* __restrict__ col,
                          int* __restrict__ cursor, int* __restrict__ packed, int EH) {
    int e = blockIdx.x * blockDim.x + threadIdx.x;
    if (e >= EH) return;
    int r = row[e];
    int c = col[e];
    int p1 = atomicAdd(&cursor[c], 1);
    packed[p1] = r;
    int p2 = atomicAdd(&cursor[r], 1);
    packed[p2] = c;
}

// --- Propagation -----------------------------------------------------------

// g0[n] = norm[n] * x[n], x = concat(ue, ie).
__global__ void lgcn_init_g0(const float* __restrict__ ue, const float* __restrict__ ie,
                             const float* __restrict__ norm, float* __restrict__ g0) {
    int t = blockIdx.x * blockDim.x + threadIdx.x; // float4 slot
    const int nT = N_NODES * (DIM / 4);
    if (t >= nT) return;
    int n = t >> 4;
    const int nU = N_USERS * (DIM / 4);
    float4 v = (t < nU) ? ((const float4*)ue)[t] : ((const float4*)ie)[t - nU];
    float nm = norm[n];
    v.x *= nm; v.y *= nm; v.z *= nm; v.w *= nm;
    ((float4*)g0)[t] = v;
}

// Pull: gn[n] = norm[n]^2 * sum_{s in N(n)} g[s].
// One 64-lane wave per node; 4 lane-groups of 16 stride the edge list by 4;
// shfl-xor(16,32) reduces the 4 partial float4s; lanes 0-15 store the row.
__global__ void lgcn_pull(const float* __restrict__ g, const int* __restrict__ rp,
                          const int* __restrict__ packed, const float* __restrict__ norm,
                          float* __restrict__ gn) {
    int n = blockIdx.x * (blockDim.x >> 6) + (threadIdx.x >> 6);
    if (n >= N_NODES) return;
    int lane = threadIdx.x & 63;
    int grp = lane >> 4;
    int c = lane & 15;
    int p0 = rp[n], p1 = rp[n + 1];
    float4 acc = make_float4(0.f, 0.f, 0.f, 0.f);
    for (int p = p0 + grp; p < p1; p += 4) {
        int s = packed[p];
        float4 v = ((const float4*)(g + (size_t)s * DIM))[c];
        acc.x += v.x; acc.y += v.y; acc.z += v.z; acc.w += v.w;
    }
#pragma unroll
    for (int off = 16; off < 64; off <<= 1) {
        acc.x += __shfl_xor(acc.x, off, 64);
        acc.y += __shfl_xor(acc.y, off, 64);
        acc.z += __shfl_xor(acc.z, off, 64);
        acc.w += __shfl_xor(acc.w, off, 64);
    }
    if (lane < 16) {
        float nm = norm[n];
        float s2 = nm * nm;
        acc.x *= s2; acc.y *= s2; acc.z *= s2; acc.w *= s2;
        ((float4*)(gn + (size_t)n * DIM))[c] = acc;
    }
}

// Layer-0 batch output: out = 0.25 * x[ids], straight from embeddings.
__global__ void lgcn_gather0(const float* __restrict__ ue, const float* __restrict__ ie,
                             const int* __restrict__ uid, const int* __restrict__ iid,
                             float* __restrict__ out) {
    int t = blockIdx.x * blockDim.x + threadIdx.x; // [0, 2*BATCH*16)
    const int half = BATCH * (DIM / 4);
    if (t >= 2 * half) return;
    int isItem = (t >= half);
    int local = t - (isItem ? half : 0);
    int b = local >> 4;
    int c = local & 15;
    const float* base = isItem ? (ie + (size_t)iid[b] * DIM)
                               : (ue + (size_t)uid[b] * DIM);
    float4 v = ((const float4*)base)[c];
    ((float4*)out)[t] = make_float4(v.x * 0.25f, v.y * 0.25f, v.z * 0.25f, v.w * 0.25f);
}

// Per-layer batch accumulate: out += 0.25 * rnorm[n] * g[n]  (== 0.25 * h[n]).
__global__ void lgcn_gather_acc(const float* __restrict__ g, const float* __restrict__ rnorm,
                                const int* __restrict__ uid, const int* __restrict__ iid,
                                float* __restrict__ out) {
    int t = blockIdx.x * blockDim.x + threadIdx.x;
    const int half = BATCH * (DIM / 4);
    if (t >= 2 * half) return;
    int isItem = (t >= half);
    int local = t - (isItem ? half : 0);
    int b = local >> 4;
    int c = local & 15;
    int n = isItem ? (N_USERS + iid[b]) : uid[b];
    float4 v = ((const float4*)(g + (size_t)n * DIM))[c];
    float s = 0.25f * rnorm[n];
    float4* o = ((float4*)out) + t;
    float4 cu = *o;
    cu.x += v.x * s; cu.y += v.y * s; cu.z += v.z * s; cu.w += v.w * s;
    *o = cu;
}

// --- Launch ----------------------------------------------------------------

extern "C" void kernel_launch(void* const* d_in, const int* in_sizes, int n_in,
                              void* d_out, int out_size, void* d_ws, size_t ws_size,
                              hipStream_t stream) {
    const float* ue  = (const float*)d_in[0];   // [N_USERS, 64]
    const float* ie  = (const float*)d_in[1];   // [N_ITEMS, 64]
    const int*   ei  = (const int*)d_in[3];     // [2, E] row-major
    const int*   uid = (const int*)d_in[4];     // [BATCH]
    const int*   iid = (const int*)d_in[5];     // [BATCH]
    float* out = (float*)d_out;

    const int E  = in_sizes[2];                 // 2,000,000 directed edges
    const int EH = E / 2;                       // 1,000,000 undirected pairs
    const int* row = ei;                        // src[0:EH] = user ids
    const int* col = ei + E;                    // dst[0:EH] = item node ids

    // Workspace carve-up (256-B aligned), ~88 MB total.
    const size_t nodeBytes = (size_t)N_NODES * DIM * sizeof(float); // 38.4 MB
    char* p = (char*)d_ws;
    size_t off = 0;
    auto carve = [&](size_t bytes) -> char* {
        char* r = p + off;
        off += (bytes + 255) & ~(size_t)255;
        return r;
    };
    float* gA       = (float*)carve(nodeBytes);
    float* gB       = (float*)carve(nodeBytes);
    int*   rp       = (int*)carve((size_t)(N_NODES + 1) * sizeof(int));
    int*   deg      = (int*)carve((size_t)N_NODES * sizeof(int));
    int*   cursor   = (int*)carve((size_t)N_NODES * sizeof(int));
    float* norm     = (float*)carve((size_t)N_NODES * sizeof(float));
    float* rnorm    = (float*)carve((size_t)N_NODES * sizeof(float));
    int*   partials = (int*)carve((size_t)CHUNK * sizeof(int));
    int*   packed   = (int*)carve((size_t)E * sizeof(int));  // 8 MB
    (void)ws_size;

    const int nScanBlks = (N_NODES + CHUNK - 1) / CHUNK;  // 147

    // 1) CSR build (per call; d_ws is re-poisoned before every launch).
    hipMemsetAsync(deg, 0, (size_t)N_NODES * sizeof(int), stream);
    lgcn_hist<<<(EH + 255) / 256, 256, 0, stream>>>(row, col, deg, EH);
    lgcn_scan1<<<nScanBlks, 256, 0, stream>>>(deg, rp, partials);
    lgcn_scan2<<<1, 256, 0, stream>>>(partials, nScanBlks);
    lgcn_scan3<<<(N_NODES + 1 + 255) / 256, 256, 0, stream>>>(
        rp, partials, cursor, deg, norm, rnorm, E);
    lgcn_fill<<<(EH + 255) / 256, 256, 0, stream>>>(row, col, cursor, packed, EH);

    // 2) Pre-scaled layer-0 features and layer-0 batch output.
    lgcn_init_g0<<<(N_NODES * (DIM / 4) + 255) / 256, 256, 0, stream>>>(ue, ie, norm, gA);
    const int gatherGrid = (2 * BATCH * (DIM / 4) + 255) / 256;
    lgcn_gather0<<<gatherGrid, 256, 0, stream>>>(ue, ie, uid, iid, out);

    // 3) Three pull layers on pre-scaled buffers.
    const int pullGrid = (N_NODES + 3) / 4;  // 4 nodes (waves) per 256-thr block
    float* cur = gA;
    float* nxt = gB;
    for (int l = 0; l < 3; ++l) {
        lgcn_pull<<<pullGrid, 256, 0, stream>>>(cur, rp, packed, norm, nxt);
        lgcn_gather_acc<<<gatherGrid, 256, 0, stream>>>(nxt, rnorm, uid, iid, out);
        float* t = cur; cur = nxt; nxt = t;
    }
}

// Round 4
// 387.562 us; speedup vs baseline: 1.5907x; 1.5907x over previous
//
#include <hip/hip_runtime.h>

// LightGCN encoder on MI355X — round 4.
// (1) Atomic-free CSR build: bin edges by dst>>10 into 147 buckets with
//     deterministic slots (LDS hist + 2-level scan), then per-bucket LDS
//     CSR build with L2-local scatter. Kills lgcn_fill's 130 MB partial-line
//     writeback and lgcn_hist's 2M global atomics.
// (2) bf16 feature buffers (fp32 accumulate, RNE store): halves pull gather
//     traffic (512 -> 256 MB/layer).
#define N_USERS 100000
#define N_NODES 150000
#define DIM 64
#define BATCH 4096
#define BSHIFT 10
#define NB 147                 // ceil(150000 / 1024) buckets
#define PAIRS_PER_BLK 8192     // undirected pairs per binning block

typedef unsigned short bf16_t;

static __device__ __forceinline__ float bf2f(bf16_t h) {
    return __uint_as_float(((unsigned)h) << 16);
}
static __device__ __forceinline__ bf16_t f2bf(float f) {  // round-nearest-even
    unsigned u = __float_as_uint(f);
    return (bf16_t)((u + 0x7FFFu + ((u >> 16) & 1u)) >> 16);
}

// --- Build step 1: per-block bucket histogram ------------------------------
__global__ void lgcn_bin_count(const int* __restrict__ row, const int* __restrict__ col,
                               int* __restrict__ blockhist, int EH) {
    __shared__ int h[NB];
    for (int i = threadIdx.x; i < NB; i += blockDim.x) h[i] = 0;
    __syncthreads();
    int k = blockIdx.x;
    int e0 = k * PAIRS_PER_BLK;
    int e1 = min(EH, e0 + PAIRS_PER_BLK);
    for (int e = e0 + threadIdx.x; e < e1; e += blockDim.x) {
        int r = row[e], c = col[e];
        atomicAdd(&h[c >> BSHIFT], 1);   // directed edge dst=c
        atomicAdd(&h[r >> BSHIFT], 1);   // directed edge dst=r
    }
    __syncthreads();
    for (int i = threadIdx.x; i < NB; i += blockDim.x)
        blockhist[k * NB + i] = h[i];
}

// --- Build step 2: per-bucket exclusive scan down the blocks ---------------
// One block per bucket (128 threads); blockhist[k][b] -> exclusive prefix,
// totals[b] = bucket size.  Requires NB1 <= 128 (2M pairs max).
__global__ void lgcn_scan_blocks(int* __restrict__ blockhist, int* __restrict__ totals,
                                 int NB1) {
    __shared__ int bufA[128], bufB[128];
    int b = blockIdx.x;
    int i = threadIdx.x;
    int v = (i < NB1) ? blockhist[i * NB + b] : 0;
    bufA[i] = v;
    __syncthreads();
    int* cur = bufA; int* nxt = bufB;
    for (int off = 1; off < 128; off <<= 1) {
        nxt[i] = (i >= off) ? cur[i] + cur[i - off] : cur[i];
        __syncthreads();
        int* t = cur; cur = nxt; nxt = t;
    }
    if (i < NB1) blockhist[i * NB + b] = cur[i] - v;   // exclusive
    if (i == 127) totals[b] = cur[127];
}

// --- Build step 3: exclusive scan over bucket totals -----------------------
__global__ void lgcn_scan_buckets(const int* __restrict__ totals,
                                  int* __restrict__ bucket_base) {
    __shared__ int bufA[256], bufB[256];
    int i = threadIdx.x;
    int v = (i < NB) ? totals[i] : 0;
    bufA[i] = v;
    __syncthreads();
    int* cur = bufA; int* nxt = bufB;
    for (int off = 1; off < 256; off <<= 1) {
        nxt[i] = (i >= off) ? cur[i] + cur[i - off] : cur[i];
        __syncthreads();
        int* t = cur; cur = nxt; nxt = t;
    }
    if (i < NB) bucket_base[i] = cur[i] - v;
    if (i == 255) bucket_base[NB] = cur[255];          // == E
}

// --- Build step 4: deterministic binning scatter ---------------------------
// Slot ranges per (block,bucket) are exclusive -> no global atomics; writes
// cluster in ~446-B runs so L2 lines fill before eviction.
// binned word = (local_dst[10b] << 18) | src[18b].
__global__ void lgcn_bin_scatter(const int* __restrict__ row, const int* __restrict__ col,
                                 const int* __restrict__ blockhist,
                                 const int* __restrict__ bucket_base,
                                 int* __restrict__ binned, int EH) {
    __shared__ int cur[NB];
    int k = blockIdx.x;
    for (int i = threadIdx.x; i < NB; i += blockDim.x)
        cur[i] = bucket_base[i] + blockhist[k * NB + i];
    __syncthreads();
    int e0 = k * PAIRS_PER_BLK;
    int e1 = min(EH, e0 + PAIRS_PER_BLK);
    for (int e = e0 + threadIdx.x; e < e1; e += blockDim.x) {
        int r = row[e], c = col[e];
        int p1 = atomicAdd(&cur[c >> BSHIFT], 1);      // LDS atomic
        binned[p1] = ((c & 1023) << 18) | r;
        int p2 = atomicAdd(&cur[r >> BSHIFT], 1);
        binned[p2] = ((r & 1023) << 18) | c;
    }
}

// --- Build step 5: per-bucket CSR (LDS hist/scan/cursors) ------------------
// Also emits rp, norm, rnorm. packed writes land in one contiguous window.
__global__ void __launch_bounds__(1024)
lgcn_build_csr(const int* __restrict__ bucket_base, const int* __restrict__ binned,
               int* __restrict__ rp, float* __restrict__ norm, float* __restrict__ rnorm,
               int* __restrict__ packed, int E) {
    __shared__ int hist[1024], sA[1024], sB[1024], cur[1024];
    int b = blockIdx.x;
    int tid = threadIdx.x;
    hist[tid] = 0;
    __syncthreads();
    int e0 = bucket_base[b], e1 = bucket_base[b + 1];
    for (int j = e0 + tid; j < e1; j += 1024)
        atomicAdd(&hist[binned[j] >> 18], 1);
    __syncthreads();
    int v = hist[tid];
    sA[tid] = v;
    __syncthreads();
    int* c_ = sA; int* n_ = sB;
    for (int off = 1; off < 1024; off <<= 1) {
        n_[tid] = (tid >= off) ? c_[tid] + c_[tid - off] : c_[tid];
        __syncthreads();
        int* t = c_; c_ = n_; n_ = t;
    }
    int excl = c_[tid] - v;
    cur[tid] = excl;
    int node = (b << BSHIFT) + tid;
    if (node < N_NODES) {
        rp[node] = e0 + excl;
        float da = (v == 0) ? 1.0f : (float)v;
        float sq = sqrtf(da);
        norm[node] = 1.0f / sq;
        rnorm[node] = sq;
    }
    if (b == NB - 1 && tid == 0) rp[N_NODES] = E;
    __syncthreads();
    for (int j = e0 + tid; j < e1; j += 1024) {
        int w = binned[j];
        int pos = atomicAdd(&cur[w >> 18], 1);         // LDS atomic
        packed[e0 + pos] = w & 0x3FFFF;                // src only
    }
}

// --- Propagation -----------------------------------------------------------

// g0[n] = norm[n] * x[n]  (bf16 out), x = concat(ue, ie).
__global__ void lgcn_init_g0(const float* __restrict__ ue, const float* __restrict__ ie,
                             const float* __restrict__ norm, bf16_t* __restrict__ g0) {
    int t = blockIdx.x * blockDim.x + threadIdx.x;     // float4-chunk slot
    const int nT = N_NODES * (DIM / 4);
    if (t >= nT) return;
    int n = t >> 4;
    const int nU = N_USERS * (DIM / 4);
    float4 x = (t < nU) ? ((const float4*)ue)[t] : ((const float4*)ie)[t - nU];
    float nm = norm[n];
    ushort4 o;
    o.x = f2bf(x.x * nm); o.y = f2bf(x.y * nm);
    o.z = f2bf(x.z * nm); o.w = f2bf(x.w * nm);
    ((ushort4*)g0)[t] = o;
}

// Pull: gn[n] = bf16( norm[n]^2 * sum_{s in N(n)} g[s] ), fp32 accumulate.
// One 64-lane wave per node; 4 groups of 16 stride the edge list; shfl-xor
// reduction; lanes 0-15 store the 128-B row.
__global__ void lgcn_pull(const bf16_t* __restrict__ g, const int* __restrict__ rp,
                          const int* __restrict__ packed, const float* __restrict__ norm,
                          bf16_t* __restrict__ gn) {
    int n = blockIdx.x * (blockDim.x >> 6) + (threadIdx.x >> 6);
    if (n >= N_NODES) return;
    int lane = threadIdx.x & 63;
    int grp = lane >> 4;
    int c = lane & 15;
    int p0 = rp[n], p1 = rp[n + 1];
    float4 acc = make_float4(0.f, 0.f, 0.f, 0.f);
    for (int p = p0 + grp; p < p1; p += 4) {
        int s = packed[p];
        ushort4 v = ((const ushort4*)(g + (size_t)s * DIM))[c];
        acc.x += bf2f(v.x); acc.y += bf2f(v.y);
        acc.z += bf2f(v.z); acc.w += bf2f(v.w);
    }
#pragma unroll
    for (int off = 16; off < 64; off <<= 1) {
        acc.x += __shfl_xor(acc.x, off, 64);
        acc.y += __shfl_xor(acc.y, off, 64);
        acc.z += __shfl_xor(acc.z, off, 64);
        acc.w += __shfl_xor(acc.w, off, 64);
    }
    if (lane < 16) {
        float nm = norm[n];
        float s2 = nm * nm;
        ushort4 o;
        o.x = f2bf(acc.x * s2); o.y = f2bf(acc.y * s2);
        o.z = f2bf(acc.z * s2); o.w = f2bf(acc.w * s2);
        ((ushort4*)(gn + (size_t)n * DIM))[c] = o;
    }
}

// Layer-0 batch output: out = 0.25 * x[ids] (exact fp32).
__global__ void lgcn_gather0(const float* __restrict__ ue, const float* __restrict__ ie,
                             const int* __restrict__ uid, const int* __restrict__ iid,
                             float* __restrict__ out) {
    int t = blockIdx.x * blockDim.x + threadIdx.x;
    const int half = BATCH * (DIM / 4);
    if (t >= 2 * half) return;
    int isItem = (t >= half);
    int local = t - (isItem ? half : 0);
    int b = local >> 4;
    int c = local & 15;
    const float* base = isItem ? (ie + (size_t)iid[b] * DIM)
                               : (ue + (size_t)uid[b] * DIM);
    float4 v = ((const float4*)base)[c];
    ((float4*)out)[t] = make_float4(v.x * 0.25f, v.y * 0.25f, v.z * 0.25f, v.w * 0.25f);
}

// Per-layer batch accumulate: out += 0.25 * rnorm[n] * g[n].
__global__ void lgcn_gather_acc(const bf16_t* __restrict__ g, const float* __restrict__ rnorm,
                                const int* __restrict__ uid, const int* __restrict__ iid,
                                float* __restrict__ out) {
    int t = blockIdx.x * blockDim.x + threadIdx.x;
    const int half = BATCH * (DIM / 4);
    if (t >= 2 * half) return;
    int isItem = (t >= half);
    int local = t - (isItem ? half : 0);
    int b = local >> 4;
    int c = local & 15;
    int n = isItem ? (N_USERS + iid[b]) : uid[b];
    ushort4 v = ((const ushort4*)(g + (size_t)n * DIM))[c];
    float s = 0.25f * rnorm[n];
    float4* o = ((float4*)out) + t;
    float4 cu = *o;
    cu.x += bf2f(v.x) * s; cu.y += bf2f(v.y) * s;
    cu.z += bf2f(v.z) * s; cu.w += bf2f(v.w) * s;
    *o = cu;
}

// --- Launch ----------------------------------------------------------------

extern "C" void kernel_launch(void* const* d_in, const int* in_sizes, int n_in,
                              void* d_out, int out_size, void* d_ws, size_t ws_size,
                              hipStream_t stream) {
    const float* ue  = (const float*)d_in[0];
    const float* ie  = (const float*)d_in[1];
    const int*   ei  = (const int*)d_in[3];
    const int*   uid = (const int*)d_in[4];
    const int*   iid = (const int*)d_in[5];
    float* out = (float*)d_out;

    const int E  = in_sizes[2];     // 2,000,000 directed edges
    const int EH = E / 2;           // 1,000,000 undirected pairs
    const int* row = ei;            // first-half src = user ids
    const int* col = ei + E;        // first-half dst = item node ids

    const int NB1 = (EH + PAIRS_PER_BLK - 1) / PAIRS_PER_BLK;   // 123 (<=128)

    // Workspace carve-up (256-B aligned), ~57 MB total.
    char* p = (char*)d_ws;
    size_t off = 0;
    auto carve = [&](size_t bytes) -> char* {
        char* r = p + off;
        off += (bytes + 255) & ~(size_t)255;
        return r;
    };
    const size_t nodeBf16 = (size_t)N_NODES * DIM * sizeof(bf16_t);   // 19.2 MB
    bf16_t* gA        = (bf16_t*)carve(nodeBf16);
    bf16_t* gB        = (bf16_t*)carve(nodeBf16);
    int*    rp        = (int*)carve((size_t)(N_NODES + 1) * sizeof(int));
    float*  norm      = (float*)carve((size_t)N_NODES * sizeof(float));
    float*  rnorm     = (float*)carve((size_t)N_NODES * sizeof(float));
    int*    blockhist = (int*)carve((size_t)128 * NB * sizeof(int));
    int*    totals    = (int*)carve((size_t)NB * sizeof(int));
    int*    bucketbase= (int*)carve((size_t)(NB + 1) * sizeof(int));
    int*    binned    = (int*)carve((size_t)E * sizeof(int));         // 8 MB
    int*    packed    = (int*)carve((size_t)E * sizeof(int));         // 8 MB
    (void)ws_size;

    // 1) Atomic-free CSR build.
    lgcn_bin_count<<<NB1, 256, 0, stream>>>(row, col, blockhist, EH);
    lgcn_scan_blocks<<<NB, 128, 0, stream>>>(blockhist, totals, NB1);
    lgcn_scan_buckets<<<1, 256, 0, stream>>>(totals, bucketbase);
    lgcn_bin_scatter<<<NB1, 256, 0, stream>>>(row, col, blockhist, bucketbase, binned, EH);
    lgcn_build_csr<<<NB, 1024, 0, stream>>>(bucketbase, binned, rp, norm, rnorm, packed, E);

    // 2) Pre-scaled bf16 layer-0 features; layer-0 batch term (exact fp32).
    lgcn_init_g0<<<(N_NODES * (DIM / 4) + 255) / 256, 256, 0, stream>>>(ue, ie, norm, gA);
    const int gatherGrid = (2 * BATCH * (DIM / 4) + 255) / 256;
    lgcn_gather0<<<gatherGrid, 256, 0, stream>>>(ue, ie, uid, iid, out);

    // 3) Three pull layers on bf16 buffers.
    const int pullGrid = (N_NODES + 3) / 4;
    bf16_t* curb = gA;
    bf16_t* nxtb = gB;
    for (int l = 0; l < 3; ++l) {
        lgcn_pull<<<pullGrid, 256, 0, stream>>>(curb, rp, packed, norm, nxtb);
        lgcn_gather_acc<<<gatherGrid, 256, 0, stream>>>(nxtb, rnorm, uid, iid, out);
        bf16_t* t = curb; curb = nxtb; nxtb = t;
    }
}

// Round 5
// 313.982 us; speedup vs baseline: 1.9635x; 1.2343x over previous
//
#include <hip/hip_runtime.h>

// LightGCN encoder on MI355X — round 5.
// Pull was dependent-load latency bound (VALUBusy 30%, HBM 18%, chain of
// ~3.3 serial idx->row hops @ ~900cy). Fix: 16-B aligned padded CSR segments,
// int4 edge-index batch load per 16-lane group, 4 ganged row loads in flight,
// invalid slots zero-weighted via FMA (no extra latency hops).
#define N_USERS 100000
#define N_NODES 150000
#define DIM 64
#define BATCH 4096
#define BSHIFT 10
#define NB 147                 // ceil(150000 / 1024) buckets
#define PAIRS_PER_BLK 8192     // undirected pairs per binning block
#define BUCKET_SLACK 4096      // padded-region slack per bucket (ints)

typedef unsigned short bf16_t;

static __device__ __forceinline__ float bf2f(bf16_t h) {
    return __uint_as_float(((unsigned)h) << 16);
}
static __device__ __forceinline__ bf16_t f2bf(float f) {  // round-nearest-even
    unsigned u = __float_as_uint(f);
    return (bf16_t)((u + 0x7FFFu + ((u >> 16) & 1u)) >> 16);
}

// --- Build step 1: per-block bucket histogram ------------------------------
__global__ void lgcn_bin_count(const int* __restrict__ row, const int* __restrict__ col,
                               int* __restrict__ blockhist, int EH) {
    __shared__ int h[NB];
    for (int i = threadIdx.x; i < NB; i += blockDim.x) h[i] = 0;
    __syncthreads();
    int k = blockIdx.x;
    int e0 = k * PAIRS_PER_BLK;
    int e1 = min(EH, e0 + PAIRS_PER_BLK);
    for (int e = e0 + threadIdx.x; e < e1; e += blockDim.x) {
        int r = row[e], c = col[e];
        atomicAdd(&h[c >> BSHIFT], 1);
        atomicAdd(&h[r >> BSHIFT], 1);
    }
    __syncthreads();
    for (int i = threadIdx.x; i < NB; i += blockDim.x)
        blockhist[k * NB + i] = h[i];
}

// --- Build step 2: per-bucket exclusive scan down the blocks ---------------
__global__ void lgcn_scan_blocks(int* __restrict__ blockhist, int* __restrict__ totals,
                                 int NB1) {
    __shared__ int bufA[128], bufB[128];
    int b = blockIdx.x;
    int i = threadIdx.x;
    int v = (i < NB1) ? blockhist[i * NB + b] : 0;
    bufA[i] = v;
    __syncthreads();
    int* cur = bufA; int* nxt = bufB;
    for (int off = 1; off < 128; off <<= 1) {
        nxt[i] = (i >= off) ? cur[i] + cur[i - off] : cur[i];
        __syncthreads();
        int* t = cur; cur = nxt; nxt = t;
    }
    if (i < NB1) blockhist[i * NB + b] = cur[i] - v;   // exclusive
    if (i == 127) totals[b] = cur[127];
}

// --- Build step 3: exclusive scan over bucket totals -----------------------
__global__ void lgcn_scan_buckets(const int* __restrict__ totals,
                                  int* __restrict__ bucket_base) {
    __shared__ int bufA[256], bufB[256];
    int i = threadIdx.x;
    int v = (i < NB) ? totals[i] : 0;
    bufA[i] = v;
    __syncthreads();
    int* cur = bufA; int* nxt = bufB;
    for (int off = 1; off < 256; off <<= 1) {
        nxt[i] = (i >= off) ? cur[i] + cur[i - off] : cur[i];
        __syncthreads();
        int* t = cur; cur = nxt; nxt = t;
    }
    if (i < NB) bucket_base[i] = cur[i] - v;
    if (i == 255) bucket_base[NB] = cur[255];          // == E
}

// --- Build step 4: deterministic binning scatter ---------------------------
// binned word = (local_dst[10b] << 18) | src[18b].
__global__ void lgcn_bin_scatter(const int* __restrict__ row, const int* __restrict__ col,
                                 const int* __restrict__ blockhist,
                                 const int* __restrict__ bucket_base,
                                 int* __restrict__ binned, int EH) {
    __shared__ int cur[NB];
    int k = blockIdx.x;
    for (int i = threadIdx.x; i < NB; i += blockDim.x)
        cur[i] = bucket_base[i] + blockhist[k * NB + i];
    __syncthreads();
    int e0 = k * PAIRS_PER_BLK;
    int e1 = min(EH, e0 + PAIRS_PER_BLK);
    for (int e = e0 + threadIdx.x; e < e1; e += blockDim.x) {
        int r = row[e], c = col[e];
        int p1 = atomicAdd(&cur[c >> BSHIFT], 1);      // LDS atomic
        binned[p1] = ((c & 1023) << 18) | r;
        int p2 = atomicAdd(&cur[r >> BSHIFT], 1);
        binned[p2] = ((r & 1023) << 18) | c;
    }
}

// --- Build step 5: per-bucket padded CSR -----------------------------------
// Node segments padded to multiple of 4 ints, bucket padded bases 16-B
// aligned -> every node start is int4-aligned. Emits nodeinfo int4:
// {start, deg, bits(1/sqrt(da)), bits(sqrt(da))}.
__global__ void __launch_bounds__(1024)
lgcn_build_csr(const int* __restrict__ bucket_base, const int* __restrict__ binned,
               int4* __restrict__ nodeinfo, int* __restrict__ packed) {
    __shared__ int hist[1024], sA[1024], sB[1024], cur[1024];
    int b = blockIdx.x;
    int tid = threadIdx.x;
    hist[tid] = 0;
    __syncthreads();
    int e0 = bucket_base[b], e1 = bucket_base[b + 1];
    for (int j = e0 + tid; j < e1; j += 1024)
        atomicAdd(&hist[binned[j] >> 18], 1);
    __syncthreads();
    int deg = hist[tid];
    int degp = (deg + 3) & ~3;                 // padded segment length
    sA[tid] = degp;
    __syncthreads();
    int* c_ = sA; int* n_ = sB;
    for (int off = 1; off < 1024; off <<= 1) {
        n_[tid] = (tid >= off) ? c_[tid] + c_[tid - off] : c_[tid];
        __syncthreads();
        int* t = c_; c_ = n_; n_ = t;
    }
    int pbase = (e0 & ~3) + BUCKET_SLACK * b;  // aligned padded bucket base
    int start = pbase + (c_[tid] - degp);      // exclusive scan, int4-aligned
    cur[tid] = start;
    int node = (b << BSHIFT) + tid;
    if (node < N_NODES) {
        float da = (deg == 0) ? 1.0f : (float)deg;
        float sq = sqrtf(da);
        int4 ni;
        ni.x = start;
        ni.y = deg;
        ni.z = __float_as_int(1.0f / sq);
        ni.w = __float_as_int(sq);
        nodeinfo[node] = ni;
    }
    __syncthreads();
    for (int j = e0 + tid; j < e1; j += 1024) {
        int w = binned[j];
        int pos = atomicAdd(&cur[w >> 18], 1); // LDS atomic
        packed[pos] = w & 0x3FFFF;             // src only
    }
}

// --- Propagation -----------------------------------------------------------

// g0[n] = norm[n] * x[n]  (bf16 out), x = concat(ue, ie).
__global__ void lgcn_init_g0(const float* __restrict__ ue, const float* __restrict__ ie,
                             const int4* __restrict__ nodeinfo, bf16_t* __restrict__ g0) {
    int t = blockIdx.x * blockDim.x + threadIdx.x;     // float4-chunk slot
    const int nT = N_NODES * (DIM / 4);
    if (t >= nT) return;
    int n = t >> 4;
    const int nU = N_USERS * (DIM / 4);
    float4 x = (t < nU) ? ((const float4*)ue)[t] : ((const float4*)ie)[t - nU];
    float nm = __int_as_float(nodeinfo[n].z);
    ushort4 o;
    o.x = f2bf(x.x * nm); o.y = f2bf(x.y * nm);
    o.z = f2bf(x.z * nm); o.w = f2bf(x.w * nm);
    ((ushort4*)g0)[t] = o;
}

// Pull: gn[n] = bf16( norm[n]^2 * sum_{s in N(n)} g[s] ), fp32 accumulate.
// One wave per node, 4 groups of 16 lanes. Each group iteration: one int4
// broadcast load of 4 edge indices, then 4 independent 128-B row loads in
// flight; invalid slots clamped (umin) and zero-weighted via FMA.
__global__ void __launch_bounds__(256)
lgcn_pull(const bf16_t* __restrict__ g, const int4* __restrict__ nodeinfo,
          const int* __restrict__ packed, bf16_t* __restrict__ gn) {
    int n = blockIdx.x * 4 + (threadIdx.x >> 6);
    if (n >= N_NODES) return;
    int lane = threadIdx.x & 63;
    int grp = lane >> 4;
    int c = lane & 15;
    int4 ni = nodeinfo[n];
    int start = ni.x;
    int deg = ni.y;
    float4 acc = make_float4(0.f, 0.f, 0.f, 0.f);
    for (int o = 4 * grp; o < deg; o += 16) {
        int4 e4 = *(const int4*)(packed + start + o);  // 16-B aligned
        int s0 = min((unsigned)e4.x, (unsigned)(N_NODES - 1));
        int s1 = min((unsigned)e4.y, (unsigned)(N_NODES - 1));
        int s2 = min((unsigned)e4.z, (unsigned)(N_NODES - 1));
        int s3 = min((unsigned)e4.w, (unsigned)(N_NODES - 1));
        ushort4 v0 = ((const ushort4*)(g + (size_t)s0 * DIM))[c];
        ushort4 v1 = ((const ushort4*)(g + (size_t)s1 * DIM))[c];
        ushort4 v2 = ((const ushort4*)(g + (size_t)s2 * DIM))[c];
        ushort4 v3 = ((const ushort4*)(g + (size_t)s3 * DIM))[c];
        float w0 = (o + 0 < deg) ? 1.0f : 0.0f;
        float w1 = (o + 1 < deg) ? 1.0f : 0.0f;
        float w2 = (o + 2 < deg) ? 1.0f : 0.0f;
        float w3 = (o + 3 < deg) ? 1.0f : 0.0f;
        acc.x = fmaf(bf2f(v0.x), w0, acc.x); acc.y = fmaf(bf2f(v0.y), w0, acc.y);
        acc.z = fmaf(bf2f(v0.z), w0, acc.z); acc.w = fmaf(bf2f(v0.w), w0, acc.w);
        acc.x = fmaf(bf2f(v1.x), w1, acc.x); acc.y = fmaf(bf2f(v1.y), w1, acc.y);
        acc.z = fmaf(bf2f(v1.z), w1, acc.z); acc.w = fmaf(bf2f(v1.w), w1, acc.w);
        acc.x = fmaf(bf2f(v2.x), w2, acc.x); acc.y = fmaf(bf2f(v2.y), w2, acc.y);
        acc.z = fmaf(bf2f(v2.z), w2, acc.z); acc.w = fmaf(bf2f(v2.w), w2, acc.w);
        acc.x = fmaf(bf2f(v3.x), w3, acc.x); acc.y = fmaf(bf2f(v3.y), w3, acc.y);
        acc.z = fmaf(bf2f(v3.z), w3, acc.z); acc.w = fmaf(bf2f(v3.w), w3, acc.w);
    }
#pragma unroll
    for (int off = 16; off < 64; off <<= 1) {
        acc.x += __shfl_xor(acc.x, off, 64);
        acc.y += __shfl_xor(acc.y, off, 64);
        acc.z += __shfl_xor(acc.z, off, 64);
        acc.w += __shfl_xor(acc.w, off, 64);
    }
    if (lane < 16) {
        float nm = __int_as_float(ni.z);
        float s2 = nm * nm;
        ushort4 o;
        o.x = f2bf(acc.x * s2); o.y = f2bf(acc.y * s2);
        o.z = f2bf(acc.z * s2); o.w = f2bf(acc.w * s2);
        ((ushort4*)(gn + (size_t)n * DIM))[c] = o;
    }
}

// Layer-0 batch output: out = 0.25 * x[ids] (exact fp32).
__global__ void lgcn_gather0(const float* __restrict__ ue, const float* __restrict__ ie,
                             const int* __restrict__ uid, const int* __restrict__ iid,
                             float* __restrict__ out) {
    int t = blockIdx.x * blockDim.x + threadIdx.x;
    const int half = BATCH * (DIM / 4);
    if (t >= 2 * half) return;
    int isItem = (t >= half);
    int local = t - (isItem ? half : 0);
    int b = local >> 4;
    int c = local & 15;
    const float* base = isItem ? (ie + (size_t)iid[b] * DIM)
                               : (ue + (size_t)uid[b] * DIM);
    float4 v = ((const float4*)base)[c];
    ((float4*)out)[t] = make_float4(v.x * 0.25f, v.y * 0.25f, v.z * 0.25f, v.w * 0.25f);
}

// Per-layer batch accumulate: out += 0.25 * rnorm[n] * g[n].
__global__ void lgcn_gather_acc(const bf16_t* __restrict__ g,
                                const int4* __restrict__ nodeinfo,
                                const int* __restrict__ uid, const int* __restrict__ iid,
                                float* __restrict__ out) {
    int t = blockIdx.x * blockDim.x + threadIdx.x;
    const int half = BATCH * (DIM / 4);
    if (t >= 2 * half) return;
    int isItem = (t >= half);
    int local = t - (isItem ? half : 0);
    int b = local >> 4;
    int c = local & 15;
    int n = isItem ? (N_USERS + iid[b]) : uid[b];
    ushort4 v = ((const ushort4*)(g + (size_t)n * DIM))[c];
    float s = 0.25f * __int_as_float(nodeinfo[n].w);
    float4* o = ((float4*)out) + t;
    float4 cu = *o;
    cu.x += bf2f(v.x) * s; cu.y += bf2f(v.y) * s;
    cu.z += bf2f(v.z) * s; cu.w += bf2f(v.w) * s;
    *o = cu;
}

// --- Launch ----------------------------------------------------------------

extern "C" void kernel_launch(void* const* d_in, const int* in_sizes, int n_in,
                              void* d_out, int out_size, void* d_ws, size_t ws_size,
                              hipStream_t stream) {
    const float* ue  = (const float*)d_in[0];
    const float* ie  = (const float*)d_in[1];
    const int*   ei  = (const int*)d_in[3];
    const int*   uid = (const int*)d_in[4];
    const int*   iid = (const int*)d_in[5];
    float* out = (float*)d_out;

    const int E  = in_sizes[2];     // 2,000,000 directed edges
    const int EH = E / 2;           // 1,000,000 undirected pairs
    const int* row = ei;            // first-half src = user ids
    const int* col = ei + E;        // first-half dst = item node ids

    const int NB1 = (EH + PAIRS_PER_BLK - 1) / PAIRS_PER_BLK;   // 123 (<=128)

    // Workspace carve-up (256-B aligned), ~62 MB total.
    char* p = (char*)d_ws;
    size_t off = 0;
    auto carve = [&](size_t bytes) -> char* {
        char* r = p + off;
        off += (bytes + 255) & ~(size_t)255;
        return r;
    };
    const size_t nodeBf16 = (size_t)N_NODES * DIM * sizeof(bf16_t);   // 19.2 MB
    bf16_t* gA        = (bf16_t*)carve(nodeBf16);
    bf16_t* gB        = (bf16_t*)carve(nodeBf16);
    int4*   nodeinfo  = (int4*)carve((size_t)N_NODES * sizeof(int4)); // 2.4 MB
    int*    blockhist = (int*)carve((size_t)128 * NB * sizeof(int));
    int*    totals    = (int*)carve((size_t)NB * sizeof(int));
    int*    bucketbase= (int*)carve((size_t)(NB + 1) * sizeof(int));
    int*    binned    = (int*)carve((size_t)E * sizeof(int));         // 8 MB
    int*    packed    = (int*)carve((size_t)(E + BUCKET_SLACK * NB + 4) * sizeof(int));
    (void)ws_size;

    // 1) Atomic-free padded CSR build.
    lgcn_bin_count<<<NB1, 256, 0, stream>>>(row, col, blockhist, EH);
    lgcn_scan_blocks<<<NB, 128, 0, stream>>>(blockhist, totals, NB1);
    lgcn_scan_buckets<<<1, 256, 0, stream>>>(totals, bucketbase);
    lgcn_bin_scatter<<<NB1, 256, 0, stream>>>(row, col, blockhist, bucketbase, binned, EH);
    lgcn_build_csr<<<NB, 1024, 0, stream>>>(bucketbase, binned, nodeinfo, packed);

    // 2) Pre-scaled bf16 layer-0 features; layer-0 batch term (exact fp32).
    lgcn_init_g0<<<(N_NODES * (DIM / 4) + 255) / 256, 256, 0, stream>>>(ue, ie, nodeinfo, gA);
    const int gatherGrid = (2 * BATCH * (DIM / 4) + 255) / 256;
    lgcn_gather0<<<gatherGrid, 256, 0, stream>>>(ue, ie, uid, iid, out);

    // 3) Three pull layers on bf16 buffers.
    const int pullGrid = (N_NODES + 3) / 4;
    bf16_t* curb = gA;
    bf16_t* nxtb = gB;
    for (int l = 0; l < 3; ++l) {
        lgcn_pull<<<pullGrid, 256, 0, stream>>>(curb, nodeinfo, packed, nxtb);
        lgcn_gather_acc<<<gatherGrid, 256, 0, stream>>>(nxtb, nodeinfo, uid, iid, out);
        bf16_t* t = curb; curb = nxtb; nxtb = t;
    }
}

// Round 6
// 239.410 us; speedup vs baseline: 2.5751x; 1.3115x over previous
//
#include <hip/hip_runtime.h>

// LightGCN encoder on MI355X — round 6.
// (1) Layer-3 computed only at the 8192 batch nodes, fused with the whole
//     epilogue (out = 0.25*(x + rn*g1 + rn*g2 + nm*sum g2[neigh])): deletes
//     one full 52-us pull + 4 gather dispatches.
// (2) Build granularity: 512-node buckets (NB=293) -> 2x blocks in build_csr,
//     9-deep scans; int4 edge reads + per-wave sub-hists in binning.
#define N_USERS 100000
#define N_NODES 150000
#define DIM 64
#define BATCH 4096
#define BSHIFT 9
#define BUCKET 512
#define NB 293                 // ceil(150000 / 512) buckets
#define PAIRS_PER_BLK 8192     // undirected pairs per binning block
#define BUCKET_SLACK 2048      // padded-region slack per bucket (ints)

typedef unsigned short bf16_t;

static __device__ __forceinline__ float bf2f(bf16_t h) {
    return __uint_as_float(((unsigned)h) << 16);
}
static __device__ __forceinline__ bf16_t f2bf(float f) {  // round-nearest-even
    unsigned u = __float_as_uint(f);
    return (bf16_t)((u + 0x7FFFu + ((u >> 16) & 1u)) >> 16);
}

// --- Build step 1: per-block bucket histogram (per-wave sub-hists) ---------
__global__ void lgcn_bin_count(const int* __restrict__ row, const int* __restrict__ col,
                               int* __restrict__ blockhist, int EH) {
    __shared__ int h[4 * NB];
    for (int i = threadIdx.x; i < 4 * NB; i += blockDim.x) h[i] = 0;
    __syncthreads();
    int k = blockIdx.x;
    int wv = threadIdx.x >> 6;
    int* hw = h + wv * NB;
    int e0 = k * PAIRS_PER_BLK;
    int e1 = min(EH, e0 + PAIRS_PER_BLK);
    int nq = (e1 - e0) >> 2;                      // both multiples of 4
    const int4* r4 = (const int4*)(row + e0);
    const int4* c4 = (const int4*)(col + e0);
    for (int q = threadIdx.x; q < nq; q += blockDim.x) {
        int4 r = r4[q];
        int4 c = c4[q];
        atomicAdd(&hw[r.x >> BSHIFT], 1); atomicAdd(&hw[c.x >> BSHIFT], 1);
        atomicAdd(&hw[r.y >> BSHIFT], 1); atomicAdd(&hw[c.y >> BSHIFT], 1);
        atomicAdd(&hw[r.z >> BSHIFT], 1); atomicAdd(&hw[c.z >> BSHIFT], 1);
        atomicAdd(&hw[r.w >> BSHIFT], 1); atomicAdd(&hw[c.w >> BSHIFT], 1);
    }
    __syncthreads();
    for (int i = threadIdx.x; i < NB; i += blockDim.x)
        blockhist[k * NB + i] = h[i] + h[NB + i] + h[2 * NB + i] + h[3 * NB + i];
}

// --- Build step 2: per-bucket exclusive scan down the blocks ---------------
__global__ void lgcn_scan_blocks(int* __restrict__ blockhist, int* __restrict__ totals,
                                 int NB1) {
    __shared__ int bufA[128], bufB[128];
    int b = blockIdx.x;
    int i = threadIdx.x;
    int v = (i < NB1) ? blockhist[i * NB + b] : 0;
    bufA[i] = v;
    __syncthreads();
    int* cur = bufA; int* nxt = bufB;
    for (int off = 1; off < 128; off <<= 1) {
        nxt[i] = (i >= off) ? cur[i] + cur[i - off] : cur[i];
        __syncthreads();
        int* t = cur; cur = nxt; nxt = t;
    }
    if (i < NB1) blockhist[i * NB + b] = cur[i] - v;   // exclusive
    if (i == 127) totals[b] = cur[127];
}

// --- Build step 3: exclusive scan over bucket totals (NB <= 512) -----------
__global__ void lgcn_scan_buckets(const int* __restrict__ totals,
                                  int* __restrict__ bucket_base) {
    __shared__ int bufA[512], bufB[512];
    int i = threadIdx.x;
    int v = (i < NB) ? totals[i] : 0;
    bufA[i] = v;
    __syncthreads();
    int* cur = bufA; int* nxt = bufB;
    for (int off = 1; off < 512; off <<= 1) {
        nxt[i] = (i >= off) ? cur[i] + cur[i - off] : cur[i];
        __syncthreads();
        int* t = cur; cur = nxt; nxt = t;
    }
    if (i < NB) bucket_base[i] = cur[i] - v;
    if (i == 511) bucket_base[NB] = cur[511];          // == E
}

// --- Build step 4: deterministic binning scatter ---------------------------
// binned word = (local_dst[9b] << 18) | src[18b].
__global__ void lgcn_bin_scatter(const int* __restrict__ row, const int* __restrict__ col,
                                 const int* __restrict__ blockhist,
                                 const int* __restrict__ bucket_base,
                                 int* __restrict__ binned, int EH) {
    __shared__ int cur[NB];
    int k = blockIdx.x;
    for (int i = threadIdx.x; i < NB; i += blockDim.x)
        cur[i] = bucket_base[i] + blockhist[k * NB + i];
    __syncthreads();
    int e0 = k * PAIRS_PER_BLK;
    int e1 = min(EH, e0 + PAIRS_PER_BLK);
    int nq = (e1 - e0) >> 2;
    const int4* r4 = (const int4*)(row + e0);
    const int4* c4 = (const int4*)(col + e0);
    for (int q = threadIdx.x; q < nq; q += blockDim.x) {
        int4 r = r4[q];
        int4 c = c4[q];
        int rr[4] = { r.x, r.y, r.z, r.w };
        int cc[4] = { c.x, c.y, c.z, c.w };
#pragma unroll
        for (int j = 0; j < 4; ++j) {
            int p1 = atomicAdd(&cur[cc[j] >> BSHIFT], 1);   // LDS atomic
            binned[p1] = ((cc[j] & (BUCKET - 1)) << 18) | rr[j];
            int p2 = atomicAdd(&cur[rr[j] >> BSHIFT], 1);
            binned[p2] = ((rr[j] & (BUCKET - 1)) << 18) | cc[j];
        }
    }
}

// --- Build step 5: per-bucket padded CSR (512-node buckets) ----------------
// Node segments padded to multiple of 4 ints; every start int4-aligned.
// nodeinfo = {start, deg, bits(1/sqrt(da)), bits(sqrt(da))}.
__global__ void __launch_bounds__(BUCKET)
lgcn_build_csr(const int* __restrict__ bucket_base, const int* __restrict__ binned,
               int4* __restrict__ nodeinfo, int* __restrict__ packed) {
    __shared__ int hist[BUCKET], sA[BUCKET], sB[BUCKET], cur[BUCKET];
    int b = blockIdx.x;
    int tid = threadIdx.x;
    hist[tid] = 0;
    __syncthreads();
    int e0 = bucket_base[b], e1 = bucket_base[b + 1];
    for (int j = e0 + tid; j < e1; j += BUCKET)
        atomicAdd(&hist[binned[j] >> 18], 1);
    __syncthreads();
    int deg = hist[tid];
    int degp = (deg + 3) & ~3;                 // padded segment length
    sA[tid] = degp;
    __syncthreads();
    int* c_ = sA; int* n_ = sB;
    for (int off = 1; off < BUCKET; off <<= 1) {
        n_[tid] = (tid >= off) ? c_[tid] + c_[tid - off] : c_[tid];
        __syncthreads();
        int* t = c_; c_ = n_; n_ = t;
    }
    int pbase = (e0 & ~3) + BUCKET_SLACK * b;  // aligned padded bucket base
    int start = pbase + (c_[tid] - degp);      // exclusive, int4-aligned
    cur[tid] = start;
    int node = (b << BSHIFT) + tid;
    if (node < N_NODES) {
        float da = (deg == 0) ? 1.0f : (float)deg;
        float sq = sqrtf(da);
        int4 ni;
        ni.x = start;
        ni.y = deg;
        ni.z = __float_as_int(1.0f / sq);
        ni.w = __float_as_int(sq);
        nodeinfo[node] = ni;
    }
    __syncthreads();
    for (int j = e0 + tid; j < e1; j += BUCKET) {
        int w = binned[j];
        int pos = atomicAdd(&cur[w >> 18], 1); // LDS atomic
        packed[pos] = w & 0x3FFFF;             // src only
    }
}

// --- Propagation -----------------------------------------------------------

// g0[n] = norm[n] * x[n]  (bf16 out), x = concat(ue, ie).
__global__ void lgcn_init_g0(const float* __restrict__ ue, const float* __restrict__ ie,
                             const int4* __restrict__ nodeinfo, bf16_t* __restrict__ g0) {
    int t = blockIdx.x * blockDim.x + threadIdx.x;     // float4-chunk slot
    const int nT = N_NODES * (DIM / 4);
    if (t >= nT) return;
    int n = t >> 4;
    const int nU = N_USERS * (DIM / 4);
    float4 x = (t < nU) ? ((const float4*)ue)[t] : ((const float4*)ie)[t - nU];
    float nm = __int_as_float(nodeinfo[n].z);
    ushort4 o;
    o.x = f2bf(x.x * nm); o.y = f2bf(x.y * nm);
    o.z = f2bf(x.z * nm); o.w = f2bf(x.w * nm);
    ((ushort4*)g0)[t] = o;
}

// Shared gather core: 16-lane group sums g rows for edges [start, start+deg).
static __device__ __forceinline__ float4
gather_sum(const bf16_t* __restrict__ g, const int* __restrict__ packed,
           int start, int deg, int grp, int c) {
    float4 acc = make_float4(0.f, 0.f, 0.f, 0.f);
    for (int o = 4 * grp; o < deg; o += 16) {
        int4 e4 = *(const int4*)(packed + start + o);  // 16-B aligned
        int s0 = min((unsigned)e4.x, (unsigned)(N_NODES - 1));
        int s1 = min((unsigned)e4.y, (unsigned)(N_NODES - 1));
        int s2 = min((unsigned)e4.z, (unsigned)(N_NODES - 1));
        int s3 = min((unsigned)e4.w, (unsigned)(N_NODES - 1));
        ushort4 v0 = ((const ushort4*)(g + (size_t)s0 * DIM))[c];
        ushort4 v1 = ((const ushort4*)(g + (size_t)s1 * DIM))[c];
        ushort4 v2 = ((const ushort4*)(g + (size_t)s2 * DIM))[c];
        ushort4 v3 = ((const ushort4*)(g + (size_t)s3 * DIM))[c];
        float w0 = (o + 0 < deg) ? 1.0f : 0.0f;
        float w1 = (o + 1 < deg) ? 1.0f : 0.0f;
        float w2 = (o + 2 < deg) ? 1.0f : 0.0f;
        float w3 = (o + 3 < deg) ? 1.0f : 0.0f;
        acc.x = fmaf(bf2f(v0.x), w0, acc.x); acc.y = fmaf(bf2f(v0.y), w0, acc.y);
        acc.z = fmaf(bf2f(v0.z), w0, acc.z); acc.w = fmaf(bf2f(v0.w), w0, acc.w);
        acc.x = fmaf(bf2f(v1.x), w1, acc.x); acc.y = fmaf(bf2f(v1.y), w1, acc.y);
        acc.z = fmaf(bf2f(v1.z), w1, acc.z); acc.w = fmaf(bf2f(v1.w), w1, acc.w);
        acc.x = fmaf(bf2f(v2.x), w2, acc.x); acc.y = fmaf(bf2f(v2.y), w2, acc.y);
        acc.z = fmaf(bf2f(v2.z), w2, acc.z); acc.w = fmaf(bf2f(v2.w), w2, acc.w);
        acc.x = fmaf(bf2f(v3.x), w3, acc.x); acc.y = fmaf(bf2f(v3.y), w3, acc.y);
        acc.z = fmaf(bf2f(v3.z), w3, acc.z); acc.w = fmaf(bf2f(v3.w), w3, acc.w);
    }
    return acc;
}

// Full pull: gn[n] = bf16( norm[n]^2 * sum_{s in N(n)} g[s] ).
__global__ void __launch_bounds__(256)
lgcn_pull(const bf16_t* __restrict__ g, const int4* __restrict__ nodeinfo,
          const int* __restrict__ packed, bf16_t* __restrict__ gn) {
    int n = blockIdx.x * 4 + (threadIdx.x >> 6);
    if (n >= N_NODES) return;
    int lane = threadIdx.x & 63;
    int grp = lane >> 4;
    int c = lane & 15;
    int4 ni = nodeinfo[n];
    float4 acc = gather_sum(g, packed, ni.x, ni.y, grp, c);
#pragma unroll
    for (int off = 16; off < 64; off <<= 1) {
        acc.x += __shfl_xor(acc.x, off, 64);
        acc.y += __shfl_xor(acc.y, off, 64);
        acc.z += __shfl_xor(acc.z, off, 64);
        acc.w += __shfl_xor(acc.w, off, 64);
    }
    if (lane < 16) {
        float nm = __int_as_float(ni.z);
        float s2 = nm * nm;
        ushort4 o;
        o.x = f2bf(acc.x * s2); o.y = f2bf(acc.y * s2);
        o.z = f2bf(acc.z * s2); o.w = f2bf(acc.w * s2);
        ((ushort4*)(gn + (size_t)n * DIM))[c] = o;
    }
}

// Fused layer-3 + epilogue, batch nodes only (8192 waves):
// out[slot] = 0.25*( x[n] + rn*g1[n] + rn*g2[n] + nm*sum_{s in N(n)} g2[s] ).
__global__ void __launch_bounds__(256)
lgcn_final(const float* __restrict__ ue, const float* __restrict__ ie,
           const bf16_t* __restrict__ g1, const bf16_t* __restrict__ g2,
           const int4* __restrict__ nodeinfo, const int* __restrict__ packed,
           const int* __restrict__ uid, const int* __restrict__ iid,
           float* __restrict__ out) {
    int slot = blockIdx.x * 4 + (threadIdx.x >> 6);
    if (slot >= 2 * BATCH) return;
    int lane = threadIdx.x & 63;
    int grp = lane >> 4;
    int c = lane & 15;
    int isItem = slot >= BATCH;
    int b = isItem ? (slot - BATCH) : slot;
    int node = isItem ? (N_USERS + iid[b]) : uid[b];
    int4 ni = nodeinfo[node];
    float4 acc = gather_sum(g2, packed, ni.x, ni.y, grp, c);
#pragma unroll
    for (int off = 16; off < 64; off <<= 1) {
        acc.x += __shfl_xor(acc.x, off, 64);
        acc.y += __shfl_xor(acc.y, off, 64);
        acc.z += __shfl_xor(acc.z, off, 64);
        acc.w += __shfl_xor(acc.w, off, 64);
    }
    if (lane < 16) {
        const float* xb = isItem ? (ie + (size_t)(node - N_USERS) * DIM)
                                 : (ue + (size_t)node * DIM);
        float4 x = ((const float4*)xb)[c];
        ushort4 a1 = ((const ushort4*)(g1 + (size_t)node * DIM))[c];
        ushort4 a2 = ((const ushort4*)(g2 + (size_t)node * DIM))[c];
        float rn = __int_as_float(ni.w);
        float nm = __int_as_float(ni.z);
        float4 r;
        r.x = 0.25f * (x.x + rn * (bf2f(a1.x) + bf2f(a2.x)) + nm * acc.x);
        r.y = 0.25f * (x.y + rn * (bf2f(a1.y) + bf2f(a2.y)) + nm * acc.y);
        r.z = 0.25f * (x.z + rn * (bf2f(a1.z) + bf2f(a2.z)) + nm * acc.z);
        r.w = 0.25f * (x.w + rn * (bf2f(a1.w) + bf2f(a2.w)) + nm * acc.w);
        ((float4*)(out + (size_t)slot * DIM))[c] = r;
    }
}

// --- Launch ----------------------------------------------------------------

extern "C" void kernel_launch(void* const* d_in, const int* in_sizes, int n_in,
                              void* d_out, int out_size, void* d_ws, size_t ws_size,
                              hipStream_t stream) {
    const float* ue  = (const float*)d_in[0];
    const float* ie  = (const float*)d_in[1];
    const int*   ei  = (const int*)d_in[3];
    const int*   uid = (const int*)d_in[4];
    const int*   iid = (const int*)d_in[5];
    float* out = (float*)d_out;

    const int E  = in_sizes[2];     // 2,000,000 directed edges
    const int EH = E / 2;           // 1,000,000 undirected pairs
    const int* row = ei;            // first-half src = user ids
    const int* col = ei + E;        // first-half dst = item node ids

    const int NB1 = (EH + PAIRS_PER_BLK - 1) / PAIRS_PER_BLK;   // 123 (<=128)

    // Workspace carve-up (256-B aligned), ~60 MB total.
    char* p = (char*)d_ws;
    size_t off = 0;
    auto carve = [&](size_t bytes) -> char* {
        char* r = p + off;
        off += (bytes + 255) & ~(size_t)255;
        return r;
    };
    const size_t nodeBf16 = (size_t)N_NODES * DIM * sizeof(bf16_t);   // 19.2 MB
    bf16_t* gA        = (bf16_t*)carve(nodeBf16);
    bf16_t* gB        = (bf16_t*)carve(nodeBf16);
    int4*   nodeinfo  = (int4*)carve((size_t)N_NODES * sizeof(int4)); // 2.4 MB
    int*    blockhist = (int*)carve((size_t)128 * NB * sizeof(int));
    int*    totals    = (int*)carve((size_t)NB * sizeof(int));
    int*    bucketbase= (int*)carve((size_t)(NB + 1) * sizeof(int));
    int*    binned    = (int*)carve((size_t)E * sizeof(int));         // 8 MB
    int*    packed    = (int*)carve((size_t)(E + BUCKET_SLACK * NB + 4) * sizeof(int));
    (void)ws_size;

    // 1) Atomic-free padded CSR build.
    lgcn_bin_count<<<NB1, 256, 0, stream>>>(row, col, blockhist, EH);
    lgcn_scan_blocks<<<NB, 128, 0, stream>>>(blockhist, totals, NB1);
    lgcn_scan_buckets<<<1, 512, 0, stream>>>(totals, bucketbase);
    lgcn_bin_scatter<<<NB1, 256, 0, stream>>>(row, col, blockhist, bucketbase, binned, EH);
    lgcn_build_csr<<<NB, BUCKET, 0, stream>>>(bucketbase, binned, nodeinfo, packed);

    // 2) g0 = norm*x (bf16).
    lgcn_init_g0<<<(N_NODES * (DIM / 4) + 255) / 256, 256, 0, stream>>>(ue, ie, nodeinfo, gA);

    // 3) Two full pulls (g1, g2), then fused batch-only layer 3 + epilogue.
    const int pullGrid = (N_NODES + 3) / 4;
    lgcn_pull<<<pullGrid, 256, 0, stream>>>(gA, nodeinfo, packed, gB);  // g1 = gB
    lgcn_pull<<<pullGrid, 256, 0, stream>>>(gB, nodeinfo, packed, gA);  // g2 = gA
    lgcn_final<<<(2 * BATCH + 3) / 4, 256, 0, stream>>>(
        ue, ie, gB, gA, nodeinfo, packed, uid, iid, out);
}

// Round 7
// 238.540 us; speedup vs baseline: 2.5845x; 1.0036x over previous
//
#include <hip/hip_runtime.h>

// LightGCN encoder on MI355X — round 7.
// (1) Single fused binning kernel: fixed-capacity bucket regions (CAP=16K),
//     per-(block,bucket) range reservation via one global atomicAdd — edge
//     order within a node segment is commutative, so the deterministic
//     3-pass scan machinery is unnecessary. 15 -> 7 dispatches.
// (2) Zero-row padding: pad slots index a zeroed row N_NODES, removing
//     per-edge clamp + weight cndmask VALU from both gather kernels.
#define N_USERS 100000
#define N_NODES 150000
#define DIM 64
#define BATCH 4096
#define BSHIFT 9
#define BUCKET 512
#define NB 293                 // ceil(150000 / 512) buckets
#define PAIRS_PER_BLK 8192     // undirected pairs per binning block
#define CAPSHIFT 14
#define CAP (1 << CAPSHIFT)    // slots per bucket region (max ~10.8K used)

typedef unsigned short bf16_t;

static __device__ __forceinline__ float bf2f(bf16_t h) {
    return __uint_as_float(((unsigned)h) << 16);
}
static __device__ __forceinline__ bf16_t f2bf(float f) {  // round-nearest-even
    unsigned u = __float_as_uint(f);
    return (bf16_t)((u + 0x7FFFu + ((u >> 16) & 1u)) >> 16);
}

// --- Fused binning: LDS hist -> range reservation -> scatter ---------------
// cursor[] must be zeroed before launch. binned word = (local_dst[9b]<<18)|src.
__global__ void lgcn_bin(const int* __restrict__ row, const int* __restrict__ col,
                         int* __restrict__ cursor, int* __restrict__ binned, int EH) {
    __shared__ int h[4 * NB];
    __shared__ int basecur[NB];
    for (int i = threadIdx.x; i < 4 * NB; i += blockDim.x) h[i] = 0;
    __syncthreads();
    int k = blockIdx.x;
    int wv = threadIdx.x >> 6;
    int* hw = h + wv * NB;
    int e0 = k * PAIRS_PER_BLK;
    int e1 = min(EH, e0 + PAIRS_PER_BLK);
    int nq = (e1 - e0) >> 2;                     // both multiples of 4
    const int4* r4 = (const int4*)(row + e0);
    const int4* c4 = (const int4*)(col + e0);
    for (int q = threadIdx.x; q < nq; q += blockDim.x) {
        int4 r = r4[q];
        int4 c = c4[q];
        atomicAdd(&hw[r.x >> BSHIFT], 1); atomicAdd(&hw[c.x >> BSHIFT], 1);
        atomicAdd(&hw[r.y >> BSHIFT], 1); atomicAdd(&hw[c.y >> BSHIFT], 1);
        atomicAdd(&hw[r.z >> BSHIFT], 1); atomicAdd(&hw[c.z >> BSHIFT], 1);
        atomicAdd(&hw[r.w >> BSHIFT], 1); atomicAdd(&hw[c.w >> BSHIFT], 1);
    }
    __syncthreads();
    for (int i = threadIdx.x; i < NB; i += blockDim.x) {
        int tot = h[i] + h[NB + i] + h[2 * NB + i] + h[3 * NB + i];
        int base = i << CAPSHIFT;
        if (tot) base += atomicAdd(&cursor[i], tot);   // reserve range
        basecur[i] = base;
    }
    __syncthreads();
    for (int q = threadIdx.x; q < nq; q += blockDim.x) {
        int4 r = r4[q];
        int4 c = c4[q];
        int rr[4] = { r.x, r.y, r.z, r.w };
        int cc[4] = { c.x, c.y, c.z, c.w };
#pragma unroll
        for (int j = 0; j < 4; ++j) {
            int p1 = atomicAdd(&basecur[cc[j] >> BSHIFT], 1);  // LDS atomic
            binned[p1] = ((cc[j] & (BUCKET - 1)) << 18) | rr[j];
            int p2 = atomicAdd(&basecur[rr[j] >> BSHIFT], 1);
            binned[p2] = ((rr[j] & (BUCKET - 1)) << 18) | cc[j];
        }
    }
}

// --- Per-bucket padded CSR -------------------------------------------------
// Node segments padded to multiple of 4; pad slots = N_NODES (zero row).
// nodeinfo = {start, deg, bits(1/sqrt(da)), bits(sqrt(da))}.
__global__ void __launch_bounds__(BUCKET)
lgcn_build_csr(const int* __restrict__ cursor, const int* __restrict__ binned,
               int4* __restrict__ nodeinfo, int* __restrict__ packed) {
    __shared__ int hist[BUCKET], sA[BUCKET], sB[BUCKET], cur[BUCKET];
    int b = blockIdx.x;
    int tid = threadIdx.x;
    hist[tid] = 0;
    __syncthreads();
    int e0 = b << CAPSHIFT;
    int e1 = e0 + cursor[b];                   // bucket edge count
    for (int j = e0 + tid; j < e1; j += BUCKET)
        atomicAdd(&hist[binned[j] >> 18], 1);
    __syncthreads();
    int deg = hist[tid];
    int degp = (deg + 3) & ~3;                 // padded segment length
    sA[tid] = degp;
    __syncthreads();
    int* c_ = sA; int* n_ = sB;
    for (int off = 1; off < BUCKET; off <<= 1) {
        n_[tid] = (tid >= off) ? c_[tid] + c_[tid - off] : c_[tid];
        __syncthreads();
        int* t = c_; c_ = n_; n_ = t;
    }
    int start = e0 + (c_[tid] - degp);         // exclusive scan, int4-aligned
    cur[tid] = start;
    int node = (b << BSHIFT) + tid;
    if (node < N_NODES) {
        float da = (deg == 0) ? 1.0f : (float)deg;
        float sq = sqrtf(da);
        int4 ni;
        ni.x = start;
        ni.y = deg;
        ni.z = __float_as_int(1.0f / sq);
        ni.w = __float_as_int(sq);
        nodeinfo[node] = ni;
    }
    __syncthreads();
    for (int j = e0 + tid; j < e1; j += BUCKET) {
        int w = binned[j];
        int pos = atomicAdd(&cur[w >> 18], 1); // LDS atomic
        packed[pos] = w & 0x3FFFF;             // src only
    }
    // Pad slots -> zero row (disjoint from all scatter targets; no sync needed).
    for (int kk = deg; kk < degp; ++kk)
        packed[start + kk] = N_NODES;
}

// --- Propagation -----------------------------------------------------------

// g0[n] = norm[n] * x[n]  (bf16), plus zero row N_NODES in BOTH buffers.
__global__ void lgcn_init_g0(const float* __restrict__ ue, const float* __restrict__ ie,
                             const int4* __restrict__ nodeinfo,
                             bf16_t* __restrict__ g0, bf16_t* __restrict__ g1) {
    int t = blockIdx.x * blockDim.x + threadIdx.x;     // ushort4-chunk slot
    const int nT = N_NODES * (DIM / 4);
    if (t >= nT) {
        if (t < nT + 16)
            ((ushort4*)g0)[nT + (t - nT)] = make_ushort4(0, 0, 0, 0);
        else if (t < nT + 32)
            ((ushort4*)g1)[nT + (t - nT - 16)] = make_ushort4(0, 0, 0, 0);
        return;
    }
    int n = t >> 4;
    const int nU = N_USERS * (DIM / 4);
    float4 x = (t < nU) ? ((const float4*)ue)[t] : ((const float4*)ie)[t - nU];
    float nm = __int_as_float(nodeinfo[n].z);
    ushort4 o;
    o.x = f2bf(x.x * nm); o.y = f2bf(x.y * nm);
    o.z = f2bf(x.z * nm); o.w = f2bf(x.w * nm);
    ((ushort4*)g0)[t] = o;
}

// Gather core: 16-lane group sums g rows for edges [start, start+deg).
// Pad slots point at the zero row -> plain adds, no clamps, no weights.
static __device__ __forceinline__ float4
gather_sum(const bf16_t* __restrict__ g, const int* __restrict__ packed,
           int start, int deg, int grp, int c) {
    float4 acc = make_float4(0.f, 0.f, 0.f, 0.f);
    for (int o = 4 * grp; o < deg; o += 16) {
        int4 e4 = *(const int4*)(packed + start + o);  // 16-B aligned
        ushort4 v0 = ((const ushort4*)(g + (size_t)e4.x * DIM))[c];
        ushort4 v1 = ((const ushort4*)(g + (size_t)e4.y * DIM))[c];
        ushort4 v2 = ((const ushort4*)(g + (size_t)e4.z * DIM))[c];
        ushort4 v3 = ((const ushort4*)(g + (size_t)e4.w * DIM))[c];
        acc.x += bf2f(v0.x); acc.y += bf2f(v0.y);
        acc.z += bf2f(v0.z); acc.w += bf2f(v0.w);
        acc.x += bf2f(v1.x); acc.y += bf2f(v1.y);
        acc.z += bf2f(v1.z); acc.w += bf2f(v1.w);
        acc.x += bf2f(v2.x); acc.y += bf2f(v2.y);
        acc.z += bf2f(v2.z); acc.w += bf2f(v2.w);
        acc.x += bf2f(v3.x); acc.y += bf2f(v3.y);
        acc.z += bf2f(v3.z); acc.w += bf2f(v3.w);
    }
    return acc;
}

// Full pull: gn[n] = bf16( norm[n]^2 * sum_{s in N(n)} g[s] ).
__global__ void __launch_bounds__(256)
lgcn_pull(const bf16_t* __restrict__ g, const int4* __restrict__ nodeinfo,
          const int* __restrict__ packed, bf16_t* __restrict__ gn) {
    int n = blockIdx.x * 4 + (threadIdx.x >> 6);
    if (n >= N_NODES) return;
    int lane = threadIdx.x & 63;
    int grp = lane >> 4;
    int c = lane & 15;
    int4 ni = nodeinfo[n];
    float4 acc = gather_sum(g, packed, ni.x, ni.y, grp, c);
#pragma unroll
    for (int off = 16; off < 64; off <<= 1) {
        acc.x += __shfl_xor(acc.x, off, 64);
        acc.y += __shfl_xor(acc.y, off, 64);
        acc.z += __shfl_xor(acc.z, off, 64);
        acc.w += __shfl_xor(acc.w, off, 64);
    }
    if (lane < 16) {
        float nm = __int_as_float(ni.z);
        float s2 = nm * nm;
        ushort4 o;
        o.x = f2bf(acc.x * s2); o.y = f2bf(acc.y * s2);
        o.z = f2bf(acc.z * s2); o.w = f2bf(acc.w * s2);
        ((ushort4*)(gn + (size_t)n * DIM))[c] = o;
    }
}

// Fused layer-3 + epilogue, batch nodes only:
// out[slot] = 0.25*( x[n] + rn*g1[n] + rn*g2[n] + nm*sum_{s in N(n)} g2[s] ).
__global__ void __launch_bounds__(256)
lgcn_final(const float* __restrict__ ue, const float* __restrict__ ie,
           const bf16_t* __restrict__ g1, const bf16_t* __restrict__ g2,
           const int4* __restrict__ nodeinfo, const int* __restrict__ packed,
           const int* __restrict__ uid, const int* __restrict__ iid,
           float* __restrict__ out) {
    int slot = blockIdx.x * 4 + (threadIdx.x >> 6);
    if (slot >= 2 * BATCH) return;
    int lane = threadIdx.x & 63;
    int grp = lane >> 4;
    int c = lane & 15;
    int isItem = slot >= BATCH;
    int b = isItem ? (slot - BATCH) : slot;
    int node = isItem ? (N_USERS + iid[b]) : uid[b];
    int4 ni = nodeinfo[node];
    float4 acc = gather_sum(g2, packed, ni.x, ni.y, grp, c);
#pragma unroll
    for (int off = 16; off < 64; off <<= 1) {
        acc.x += __shfl_xor(acc.x, off, 64);
        acc.y += __shfl_xor(acc.y, off, 64);
        acc.z += __shfl_xor(acc.z, off, 64);
        acc.w += __shfl_xor(acc.w, off, 64);
    }
    if (lane < 16) {
        const float* xb = isItem ? (ie + (size_t)(node - N_USERS) * DIM)
                                 : (ue + (size_t)node * DIM);
        float4 x = ((const float4*)xb)[c];
        ushort4 a1 = ((const ushort4*)(g1 + (size_t)node * DIM))[c];
        ushort4 a2 = ((const ushort4*)(g2 + (size_t)node * DIM))[c];
        float rn = __int_as_float(ni.w);
        float nm = __int_as_float(ni.z);
        float4 r;
        r.x = 0.25f * (x.x + rn * (bf2f(a1.x) + bf2f(a2.x)) + nm * acc.x);
        r.y = 0.25f * (x.y + rn * (bf2f(a1.y) + bf2f(a2.y)) + nm * acc.y);
        r.z = 0.25f * (x.z + rn * (bf2f(a1.z) + bf2f(a2.z)) + nm * acc.z);
        r.w = 0.25f * (x.w + rn * (bf2f(a1.w) + bf2f(a2.w)) + nm * acc.w);
        ((float4*)(out + (size_t)slot * DIM))[c] = r;
    }
}

// --- Launch ----------------------------------------------------------------

extern "C" void kernel_launch(void* const* d_in, const int* in_sizes, int n_in,
                              void* d_out, int out_size, void* d_ws, size_t ws_size,
                              hipStream_t stream) {
    const float* ue  = (const float*)d_in[0];
    const float* ie  = (const float*)d_in[1];
    const int*   ei  = (const int*)d_in[3];
    const int*   uid = (const int*)d_in[4];
    const int*   iid = (const int*)d_in[5];
    float* out = (float*)d_out;

    const int E  = in_sizes[2];     // 2,000,000 directed edges
    const int EH = E / 2;           // 1,000,000 undirected pairs
    const int* row = ei;            // first-half src = user ids
    const int* col = ei + E;        // first-half dst = item node ids
    (void)E;

    const int NB1 = (EH + PAIRS_PER_BLK - 1) / PAIRS_PER_BLK;   // 123

    // Workspace carve-up (256-B aligned), ~80 MB total.
    char* p = (char*)d_ws;
    size_t off = 0;
    auto carve = [&](size_t bytes) -> char* {
        char* r = p + off;
        off += (bytes + 255) & ~(size_t)255;
        return r;
    };
    const size_t nodeBf16 = (size_t)(N_NODES + 1) * DIM * sizeof(bf16_t); // +zero row
    bf16_t* gA       = (bf16_t*)carve(nodeBf16);
    bf16_t* gB       = (bf16_t*)carve(nodeBf16);
    int4*   nodeinfo = (int4*)carve((size_t)N_NODES * sizeof(int4));     // 2.4 MB
    int*    cursor   = (int*)carve((size_t)NB * sizeof(int));
    int*    binned   = (int*)carve((size_t)NB * CAP * sizeof(int));      // 19.2 MB
    int*    packed   = (int*)carve((size_t)NB * CAP * sizeof(int));      // 19.2 MB
    (void)ws_size;

    // 1) Binning (cursor must start at zero) + per-bucket CSR.
    hipMemsetAsync(cursor, 0, (size_t)NB * sizeof(int), stream);
    lgcn_bin<<<NB1, 256, 0, stream>>>(row, col, cursor, binned, EH);
    lgcn_build_csr<<<NB, BUCKET, 0, stream>>>(cursor, binned, nodeinfo, packed);

    // 2) g0 = norm*x (bf16) + zero rows in both buffers.
    lgcn_init_g0<<<(N_NODES * (DIM / 4) + 32 + 255) / 256, 256, 0, stream>>>(
        ue, ie, nodeinfo, gA, gB);

    // 3) Two full pulls (g1, g2), then fused batch-only layer 3 + epilogue.
    const int pullGrid = (N_NODES + 3) / 4;
    lgcn_pull<<<pullGrid, 256, 0, stream>>>(gA, nodeinfo, packed, gB);  // g1 = gB
    lgcn_pull<<<pullGrid, 256, 0, stream>>>(gB, nodeinfo, packed, gA);  // g2 = gA
    lgcn_final<<<(2 * BATCH + 3) / 4, 256, 0, stream>>>(
        ue, ie, gB, gA, nodeinfo, packed, uid, iid, out);
}